// Round 1
// baseline (653.796 us; speedup 1.0000x reference)
//
#include <hip/hip_runtime.h>
#include <hip/hip_bf16.h>
#include <hip/hip_fp16.h>

typedef _Float16 half8 __attribute__((ext_vector_type(8)));
typedef _Float16 half4 __attribute__((ext_vector_type(4)));
typedef float f32x4 __attribute__((ext_vector_type(4)));

#define LN_EPS 1e-5f
#define MASK_FILL -1e9f

// ---------------- cast f32 -> f16 (vec4) ----------------
__global__ __launch_bounds__(256) void cast_f32_f16_kernel(
    const float* __restrict__ in, _Float16* __restrict__ out, int n4) {
  int i = blockIdx.x * 256 + threadIdx.x;
  if (i < n4) {
    float4 v = ((const float4*)in)[i];
    half4 h = { (_Float16)v.x, (_Float16)v.y, (_Float16)v.z, (_Float16)v.w };
    ((half4*)out)[i] = h;
  }
}

// ---------------- transpose f32 [R][C] -> f16 [C][R] ----------------
__global__ __launch_bounds__(256) void transpose_f32_to_f16_kernel(
    const float* __restrict__ in, _Float16* __restrict__ out, int R, int C) {
  __shared__ float tile[32][33];
  int bc = blockIdx.x * 32, br = blockIdx.y * 32;
  int lc = threadIdx.x & 31;
  int lr0 = threadIdx.x >> 5;  // 0..7
  for (int i = lr0; i < 32; i += 8)
    tile[i][lc] = in[(size_t)(br + i) * C + bc + lc];
  __syncthreads();
  for (int i = lr0; i < 32; i += 8)
    out[(size_t)(bc + i) * R + br + lc] = (_Float16)tile[lc][i];
}

// ---------------- fp16 MFMA GEMM: C[M][N] = alpha * A[M][K] @ Bt[N][K]^T ----
// 128x128 tile, BK=32, 4 waves (2x2), each wave 64x64 via 4x4 16x16x32 frags.
template<bool OUT_F32>
__global__ __launch_bounds__(256) void gemm_f16_kernel(
    const _Float16* __restrict__ A, const _Float16* __restrict__ Bt,
    void* __restrict__ C, int M, int N, int K, float alpha) {
  __shared__ _Float16 As[128][40];
  __shared__ _Float16 Bs[128][40];
  const int tid = threadIdx.x;
  const int bm = blockIdx.x * 128, bn = blockIdx.y * 128;
  const int wave = tid >> 6, lane = tid & 63;
  const int wr = (wave >> 1) * 64, wc = (wave & 1) * 64;
  const int fr = lane & 15, kg = (lane >> 4) * 8;
  f32x4 acc[4][4] = {};
  const int ar = tid >> 1;
  const int ac = (tid & 1) * 16;
  const _Float16* ap = A + (size_t)(bm + ar) * K + ac;
  const _Float16* bp = Bt + (size_t)(bn + ar) * K + ac;
  for (int k0 = 0; k0 < K; k0 += 32) {
    half8 av0 = *(const half8*)(ap + k0);
    half8 av1 = *(const half8*)(ap + k0 + 8);
    half8 bv0 = *(const half8*)(bp + k0);
    half8 bv1 = *(const half8*)(bp + k0 + 8);
    __syncthreads();
    *(half8*)&As[ar][ac] = av0;
    *(half8*)&As[ar][ac + 8] = av1;
    *(half8*)&Bs[ar][ac] = bv0;
    *(half8*)&Bs[ar][ac + 8] = bv1;
    __syncthreads();
    half8 af[4], bf[4];
#pragma unroll
    for (int i = 0; i < 4; i++) af[i] = *(const half8*)&As[wr + i * 16 + fr][kg];
#pragma unroll
    for (int j = 0; j < 4; j++) bf[j] = *(const half8*)&Bs[wc + j * 16 + fr][kg];
#pragma unroll
    for (int i = 0; i < 4; i++)
#pragma unroll
      for (int j = 0; j < 4; j++)
        acc[i][j] = __builtin_amdgcn_mfma_f32_16x16x32_f16(af[i], bf[j], acc[i][j], 0, 0, 0);
  }
  const int rg = (lane >> 4) * 4;
#pragma unroll
  for (int i = 0; i < 4; i++) {
#pragma unroll
    for (int j = 0; j < 4; j++) {
      int col = bn + wc + j * 16 + fr;
#pragma unroll
      for (int r = 0; r < 4; r++) {
        int row = bm + wr + i * 16 + rg + r;
        float v = acc[i][j][r] * alpha;
        if (OUT_F32)
          ((float*)C)[(size_t)row * N + col] = v;
        else
          ((_Float16*)C)[(size_t)row * N + col] = (_Float16)v;
      }
    }
  }
}

// ---------------- block reduce helper (256 threads, 4 waves) ----------------
__device__ __forceinline__ float block_reduce(float v, bool do_max, float* wbuf, int tid) {
#pragma unroll
  for (int m = 32; m; m >>= 1) {
    float o = __shfl_xor(v, m);
    v = do_max ? fmaxf(v, o) : (v + o);
  }
  if ((tid & 63) == 0) wbuf[tid >> 6] = v;
  __syncthreads();
  float r = do_max ? fmaxf(fmaxf(wbuf[0], wbuf[1]), fmaxf(wbuf[2], wbuf[3]))
                   : (wbuf[0] + wbuf[1] + wbuf[2] + wbuf[3]);
  __syncthreads();
  return r;
}

// ---------------- softmax over n + ds-weighted combine ----------------
// One block per (k-description). S is [2048][4096] for this batch.
// ca[kd][n] = sum_ds w(kd,ds) * softmax_n(att[kd,ds,:])[n]
__global__ __launch_bounds__(256) void softmax_combine_kernel(
    const _Float16* __restrict__ S, const int* __restrict__ desc_mask,
    const int* __restrict__ note_mask, float* __restrict__ ca) {
  __shared__ float wbuf[4];
  const int kd = blockIdx.x;  // 0..63
  const int tid = threadIdx.x;
  bool nm[16];
#pragma unroll
  for (int c = 0; c < 16; c++) nm[c] = note_mask[c * 256 + tid] != 0;
  int nv = 0;
  for (int dsI = 0; dsI < 32; ++dsI) nv += (desc_mask[kd * 32 + dsI] != 0);
  const float wbase = nv ? (1.0f / (float)nv) : (1.0f / 32.0f);
  float ca_r[16];
#pragma unroll
  for (int c = 0; c < 16; c++) ca_r[c] = 0.f;
  for (int dsI = 0; dsI < 32; ++dsI) {
    const bool dm = desc_mask[kd * 32 + dsI] != 0;
    const float w = nv ? (dm ? wbase : 0.0f) : wbase;
    if (w == 0.0f) continue;  // block-uniform branch
    const _Float16* srow = S + (size_t)(kd * 32 + dsI) * 4096;
    float a[16];
#pragma unroll
    for (int c = 0; c < 16; c++) {
      float s = (float)srow[c * 256 + tid];
      a[c] = (dm && nm[c]) ? s : MASK_FILL;
    }
    float mx = a[0];
#pragma unroll
    for (int c = 1; c < 16; c++) mx = fmaxf(mx, a[c]);
    mx = block_reduce(mx, true, wbuf, tid);
    float e[16];
    float ls = 0.f;
#pragma unroll
    for (int c = 0; c < 16; c++) {
      e[c] = expf(a[c] - mx);
      ls += e[c];
    }
    float denom = block_reduce(ls, false, wbuf, tid);
    float iw = w / denom;
#pragma unroll
    for (int c = 0; c < 16; c++) ca_r[c] += iw * e[c];
  }
#pragma unroll
  for (int c = 0; c < 16; c++) ca[(size_t)kd * 4096 + c * 256 + tid] = ca_r[c];
}

// ---------------- t partial: t[b*64+m][j] = sum_n ca[b][m][n] * x[b][n][j] ----
// fp32 vector path (exact x). Partials over 16 n-chunks of 256.
__global__ __launch_bounds__(256) void t_partial_kernel(
    const float* __restrict__ ca,   // [4][64][4096]
    const float* __restrict__ x,    // [4][4096][768]
    float* __restrict__ t_part) {   // [16][256][768]
  __shared__ float cas[64][68];
  __shared__ float xs[64][68];
  const int jt = blockIdx.x;  // 0..11
  const int nc = blockIdx.y;  // 0..15
  const int b = blockIdx.z;   // 0..3
  const int tid = threadIdx.x;
  const int tm = tid >> 4, tj = tid & 15;
  const int r = tid >> 2, cg = (tid & 3) * 16;
  float acc[4][4] = {};
  for (int n0 = nc * 256; n0 < nc * 256 + 256; n0 += 64) {
    __syncthreads();
    const float* cap = ca + ((size_t)(b * 64 + r)) * 4096 + n0 + cg;
    const float* xp = x + ((size_t)b * 4096 + n0 + r) * 768 + jt * 64 + cg;
#pragma unroll
    for (int u = 0; u < 16; u += 4) {
      *(float4*)&cas[r][cg + u] = *(const float4*)(cap + u);
      *(float4*)&xs[r][cg + u] = *(const float4*)(xp + u);
    }
    __syncthreads();
#pragma unroll 16
    for (int nn = 0; nn < 64; ++nn) {
      float cm[4], xj[4];
#pragma unroll
      for (int i = 0; i < 4; i++) cm[i] = cas[tm * 4 + i][nn];
#pragma unroll
      for (int j = 0; j < 4; j++) xj[j] = xs[nn][tj * 4 + j];
#pragma unroll
      for (int i = 0; i < 4; i++)
#pragma unroll
        for (int j = 0; j < 4; j++) acc[i][j] += cm[i] * xj[j];
    }
  }
#pragma unroll
  for (int i = 0; i < 4; i++)
#pragma unroll
    for (int j = 0; j < 4; j++)
      t_part[((size_t)nc * 256 + b * 64 + tm * 4 + i) * 768 + jt * 64 + tj * 4 + j] = acc[i][j];
}

__global__ __launch_bounds__(256) void t_reduce_kernel(
    const float* __restrict__ t_part, float* __restrict__ t) {
  int i = blockIdx.x * 256 + threadIdx.x;  // < 196608
  float s = 0.f;
#pragma unroll
  for (int nc = 0; nc < 16; ++nc) s += t_part[(size_t)nc * 196608 + i];
  t[i] = s;
}

// ---------------- LayerNorm + final projection ----------------
__global__ __launch_bounds__(256) void ln_out_kernel(
    const float* __restrict__ pooled, const float* __restrict__ Wo,
    const float* __restrict__ bo, const float* __restrict__ gamma,
    const float* __restrict__ beta, float* __restrict__ out) {
  __shared__ float wbuf[4];
  const int row = blockIdx.x, tid = threadIdx.x;
  float p[3];
#pragma unroll
  for (int u = 0; u < 3; u++) p[u] = pooled[(size_t)row * 768 + tid + u * 256];
  float s1 = p[0] + p[1] + p[2];
  float s2 = p[0] * p[0] + p[1] * p[1] + p[2] * p[2];
  s1 = block_reduce(s1, false, wbuf, tid);
  s2 = block_reduce(s2, false, wbuf, tid);
  float mean = s1 * (1.f / 768.f);
  float var = s2 * (1.f / 768.f) - mean * mean;
  float rstd = rsqrtf(var + LN_EPS);
  float accv = 0.f;
#pragma unroll
  for (int u = 0; u < 3; u++) {
    int i = tid + u * 256;
    float y = (p[u] - mean) * rstd * gamma[i] + beta[i];
    accv += y * Wo[i];
  }
  accv = block_reduce(accv, false, wbuf, tid);
  if (tid == 0) out[row] = accv + bo[0];
}

extern "C" void kernel_launch(void* const* d_in, const int* in_sizes, int n_in,
                              void* d_out, int out_size, void* d_ws, size_t ws_size,
                              hipStream_t stream) {
  const float* x = (const float*)d_in[0];
  const float* enc = (const float*)d_in[1];
  const int* dmask = (const int*)d_in[2];
  const int* amask = (const int*)d_in[3];
  const float* Wk = (const float*)d_in[4];
  const float* Wv = (const float*)d_in[5];
  const float* Wo = (const float*)d_in[6];
  const float* bo = (const float*)d_in[7];
  const float* gamma = (const float*)d_in[8];
  const float* beta = (const float*)d_in[9];
  float* out = (float*)d_out;

  char* ws = (char*)d_ws;
  size_t off = 0;
  auto alloc = [&](size_t bytes) -> char* {
    char* p = ws + off;
    off += (bytes + 255) & ~((size_t)255);
    return p;
  };
  _Float16* xh = (_Float16*)alloc((size_t)16384 * 768 * 2);
  _Float16* ench = (_Float16*)alloc((size_t)2048 * 768 * 2);
  _Float16* wkT = (_Float16*)alloc((size_t)768 * 768 * 2);
  _Float16* wvh = (_Float16*)alloc((size_t)768 * 768 * 2);
  _Float16* encKh = (_Float16*)alloc((size_t)2048 * 768 * 2);
  _Float16* S = (_Float16*)alloc((size_t)2048 * 4096 * 2);
  float* ca = (float*)alloc((size_t)4 * 64 * 4096 * 4);
  float* t_part = (float*)alloc((size_t)16 * 256 * 768 * 4);
  float* t = (float*)alloc((size_t)256 * 768 * 4);
  _Float16* th = (_Float16*)alloc((size_t)256 * 768 * 2);
  float* pooled = (float*)alloc((size_t)256 * 768 * 4);

  const float scale = 0.036084391824351615f;  // 1/sqrt(768)

  cast_f32_f16_kernel<<<12288, 256, 0, stream>>>(x, xh, 16384 * 768 / 4);
  cast_f32_f16_kernel<<<1536, 256, 0, stream>>>(enc, ench, 2048 * 768 / 4);
  cast_f32_f16_kernel<<<576, 256, 0, stream>>>(Wv, wvh, 768 * 768 / 4);
  transpose_f32_to_f16_kernel<<<dim3(24, 24), 256, 0, stream>>>(Wk, wkT, 768, 768);

  // encK = enc @ Wk   [2048 x 768]
  gemm_f16_kernel<false><<<dim3(16, 6), 256, 0, stream>>>(ench, wkT, encKh, 2048, 768, 768, 1.0f);

  for (int b = 0; b < 4; b++) {
    // S = scale * encK @ x_b^T   [2048 x 4096]
    gemm_f16_kernel<false><<<dim3(16, 32), 256, 0, stream>>>(
        encKh, xh + (size_t)b * 4096 * 768, S, 2048, 4096, 768, scale);
    softmax_combine_kernel<<<64, 256, 0, stream>>>(
        S, dmask, amask + b * 4096, ca + (size_t)b * 64 * 4096);
  }
  // t = ca @ x  (fp32), split over n-chunks then reduced
  t_partial_kernel<<<dim3(12, 16, 4), 256, 0, stream>>>(ca, x, t_part);
  t_reduce_kernel<<<768, 256, 0, stream>>>(t_part, t);
  cast_f32_f16_kernel<<<192, 256, 0, stream>>>(t, th, 196608 / 4);
  // pooled = t @ Wv^T  [256 x 768] fp32
  gemm_f16_kernel<true><<<dim3(2, 6), 256, 0, stream>>>(th, wvh, pooled, 256, 768, 768, 1.0f);
  ln_out_kernel<<<256, 256, 0, stream>>>(pooled, Wo, bo, gamma, beta, out);
}

// Round 2
// 225.449 us; speedup vs baseline: 2.9000x; 2.9000x over previous
//
#include <hip/hip_runtime.h>
#include <hip/hip_bf16.h>
#include <hip/hip_fp16.h>

typedef _Float16 half8 __attribute__((ext_vector_type(8)));
typedef _Float16 half4 __attribute__((ext_vector_type(4)));
typedef float f32x4 __attribute__((ext_vector_type(4)));

#define LN_EPS 1e-5f
#define MASK_FILL -1e9f

// ---------------- cast f32 -> f16 (vec4) ----------------
__global__ __launch_bounds__(256) void cast_f32_f16_kernel(
    const float* __restrict__ in, _Float16* __restrict__ out, int n4) {
  int i = blockIdx.x * 256 + threadIdx.x;
  if (i < n4) {
    float4 v = ((const float4*)in)[i];
    half4 h = { (_Float16)v.x, (_Float16)v.y, (_Float16)v.z, (_Float16)v.w };
    ((half4*)out)[i] = h;
  }
}

// ---------------- transpose f32 [R][C] -> f16 [C][R] ----------------
__global__ __launch_bounds__(256) void transpose_f32_to_f16_kernel(
    const float* __restrict__ in, _Float16* __restrict__ out, int R, int C) {
  __shared__ float tile[32][33];
  int bc = blockIdx.x * 32, br = blockIdx.y * 32;
  int lc = threadIdx.x & 31;
  int lr0 = threadIdx.x >> 5;  // 0..7
  for (int i = lr0; i < 32; i += 8)
    tile[i][lc] = in[(size_t)(br + i) * C + bc + lc];
  __syncthreads();
  for (int i = lr0; i < 32; i += 8)
    out[(size_t)(bc + i) * R + br + lc] = (_Float16)tile[lc][i];
}

// ---------------- fp16 MFMA GEMM: C[M][N] = alpha * A[M][K] @ Bt[N][K]^T ----
// 128x128 tile, BK=32, 4 waves (2x2), each wave 64x64 via 4x4 16x16x32 frags.
// Optional z-batch over Bt/C via element strides.
template<bool OUT_F32>
__global__ __launch_bounds__(256) void gemm_f16_kernel(
    const _Float16* __restrict__ A, const _Float16* __restrict__ Bt,
    void* __restrict__ C, int M, int N, int K, float alpha,
    size_t strideBt, size_t strideC) {
  __shared__ _Float16 As[128][40];
  __shared__ _Float16 Bs[128][40];
  const int tid = threadIdx.x;
  const int bm = blockIdx.x * 128, bn = blockIdx.y * 128;
  const size_t z = blockIdx.z;
  const int wave = tid >> 6, lane = tid & 63;
  const int wr = (wave >> 1) * 64, wc = (wave & 1) * 64;
  const int fr = lane & 15, kg = (lane >> 4) * 8;
  f32x4 acc[4][4] = {};
  const int ar = tid >> 1;
  const int ac = (tid & 1) * 16;
  const _Float16* ap = A + (size_t)(bm + ar) * K + ac;
  const _Float16* bp = Bt + z * strideBt + (size_t)(bn + ar) * K + ac;
  for (int k0 = 0; k0 < K; k0 += 32) {
    half8 av0 = *(const half8*)(ap + k0);
    half8 av1 = *(const half8*)(ap + k0 + 8);
    half8 bv0 = *(const half8*)(bp + k0);
    half8 bv1 = *(const half8*)(bp + k0 + 8);
    __syncthreads();
    *(half8*)&As[ar][ac] = av0;
    *(half8*)&As[ar][ac + 8] = av1;
    *(half8*)&Bs[ar][ac] = bv0;
    *(half8*)&Bs[ar][ac + 8] = bv1;
    __syncthreads();
    half8 af[4], bf[4];
#pragma unroll
    for (int i = 0; i < 4; i++) af[i] = *(const half8*)&As[wr + i * 16 + fr][kg];
#pragma unroll
    for (int j = 0; j < 4; j++) bf[j] = *(const half8*)&Bs[wc + j * 16 + fr][kg];
#pragma unroll
    for (int i = 0; i < 4; i++)
#pragma unroll
      for (int j = 0; j < 4; j++)
        acc[i][j] = __builtin_amdgcn_mfma_f32_16x16x32_f16(af[i], bf[j], acc[i][j], 0, 0, 0);
  }
  const int rg = (lane >> 4) * 4;
#pragma unroll
  for (int i = 0; i < 4; i++) {
#pragma unroll
    for (int j = 0; j < 4; j++) {
      int col = bn + wc + j * 16 + fr;
#pragma unroll
      for (int r = 0; r < 4; r++) {
        int row = bm + wr + i * 16 + rg + r;
        float v = acc[i][j][r] * alpha;
        if (OUT_F32)
          ((float*)C)[z * strideC + (size_t)row * N + col] = v;
        else
          ((_Float16*)C)[z * strideC + (size_t)row * N + col] = (_Float16)v;
      }
    }
  }
}

// ---------------- block reduce helper (256 threads, 4 waves) ----------------
__device__ __forceinline__ float block_reduce(float v, bool do_max, float* wbuf, int tid) {
#pragma unroll
  for (int m = 32; m; m >>= 1) {
    float o = __shfl_xor(v, m);
    v = do_max ? fmaxf(v, o) : (v + o);
  }
  if ((tid & 63) == 0) wbuf[tid >> 6] = v;
  __syncthreads();
  float r = do_max ? fmaxf(fmaxf(wbuf[0], wbuf[1]), fmaxf(wbuf[2], wbuf[3]))
                   : (wbuf[0] + wbuf[1] + wbuf[2] + wbuf[3]);
  __syncthreads();
  return r;
}

// ---------------- pass 1: per-row masked softmax stats ----------------
// One block per S-row. stats[b*2048+row] = (rowmax, w/denom, dm_flag, 0)
__global__ __launch_bounds__(256) void row_stats_kernel(
    const _Float16* __restrict__ S, const int* __restrict__ dmask,
    const int* __restrict__ amask, float4* __restrict__ stats) {
  __shared__ float wbuf[4];
  const int row = blockIdx.x;  // 0..2047 (= kd*32+ds)
  const int b = blockIdx.z;
  const int tid = threadIdx.x;
  const int kd = row >> 5;
  const bool dm = dmask[row] != 0;
  int nv = 0;
#pragma unroll
  for (int i = 0; i < 32; i++) nv += (dmask[kd * 32 + i] != 0);
  const float w = nv ? (dm ? 1.0f / (float)nv : 0.0f) : (1.0f / 32.0f);
  if (w == 0.0f) {
    if (tid == 0) stats[(size_t)b * 2048 + row] = make_float4(0.f, 0.f, 0.f, 0.f);
    return;
  }
  const _Float16* sp = S + ((size_t)b * 2048 + row) * 4096;
  const int* am = amask + (size_t)b * 4096;
  float a[16];
#pragma unroll
  for (int c = 0; c < 16; c++) {
    float s = (float)sp[c * 256 + tid];
    bool nm = am[c * 256 + tid] != 0;
    a[c] = (dm && nm) ? s : MASK_FILL;
  }
  float mx = a[0];
#pragma unroll
  for (int c = 1; c < 16; c++) mx = fmaxf(mx, a[c]);
  mx = block_reduce(mx, true, wbuf, tid);
  float ls = 0.f;
#pragma unroll
  for (int c = 0; c < 16; c++) ls += expf(a[c] - mx);
  float denom = block_reduce(ls, false, wbuf, tid);
  if (tid == 0)
    stats[(size_t)b * 2048 + row] = make_float4(mx, w / denom, dm ? 1.f : 0.f, 0.f);
}

// ---------------- pass 2: ds-weighted combine ----------------
// ca[b][kd][n] = sum_ds iw * exp(a - mx); one thread per n-column.
__global__ __launch_bounds__(256) void combine_kernel(
    const _Float16* __restrict__ S, const float4* __restrict__ stats,
    const int* __restrict__ amask, float* __restrict__ ca) {
  const int kd = blockIdx.x;
  const int b = blockIdx.z;
  const int n = blockIdx.y * 256 + threadIdx.x;
  const bool nm = amask[(size_t)b * 4096 + n] != 0;
  const _Float16* sp = S + ((size_t)b * 2048 + kd * 32) * 4096 + n;
  const float4* st = stats + (size_t)b * 2048 + kd * 32;
  float acc = 0.f;
#pragma unroll
  for (int ds = 0; ds < 32; ds++) {
    float4 s4 = st[ds];
    if (s4.y == 0.f) continue;
    float s = (float)sp[(size_t)ds * 4096];
    float a = (s4.z != 0.f && nm) ? s : MASK_FILL;
    acc += s4.y * expf(a - s4.x);
  }
  ca[((size_t)b * 64 + kd) * 4096 + n] = acc;
}

// ---------------- t partial: t[b*64+m][j] = sum_n ca[b][m][n] * x[b][n][j] ----
__global__ __launch_bounds__(256) void t_partial_kernel(
    const float* __restrict__ ca,   // [4][64][4096]
    const float* __restrict__ x,    // [4][4096][768]
    float* __restrict__ t_part) {   // [16][256][768]
  __shared__ float cas[64][68];
  __shared__ float xs[64][68];
  const int jt = blockIdx.x;  // 0..11
  const int nc = blockIdx.y;  // 0..15
  const int b = blockIdx.z;   // 0..3
  const int tid = threadIdx.x;
  const int tm = tid >> 4, tj = tid & 15;
  const int r = tid >> 2, cg = (tid & 3) * 16;
  float acc[4][4] = {};
  for (int n0 = nc * 256; n0 < nc * 256 + 256; n0 += 64) {
    __syncthreads();
    const float* cap = ca + ((size_t)(b * 64 + r)) * 4096 + n0 + cg;
    const float* xp = x + ((size_t)b * 4096 + n0 + r) * 768 + jt * 64 + cg;
#pragma unroll
    for (int u = 0; u < 16; u += 4) {
      *(float4*)&cas[r][cg + u] = *(const float4*)(cap + u);
      *(float4*)&xs[r][cg + u] = *(const float4*)(xp + u);
    }
    __syncthreads();
#pragma unroll 16
    for (int nn = 0; nn < 64; ++nn) {
      float cm[4], xj[4];
#pragma unroll
      for (int i = 0; i < 4; i++) cm[i] = cas[tm * 4 + i][nn];
#pragma unroll
      for (int j = 0; j < 4; j++) xj[j] = xs[nn][tj * 4 + j];
#pragma unroll
      for (int i = 0; i < 4; i++)
#pragma unroll
        for (int j = 0; j < 4; j++) acc[i][j] += cm[i] * xj[j];
    }
  }
#pragma unroll
  for (int i = 0; i < 4; i++)
#pragma unroll
    for (int j = 0; j < 4; j++)
      t_part[((size_t)nc * 256 + b * 64 + tm * 4 + i) * 768 + jt * 64 + tj * 4 + j] = acc[i][j];
}

__global__ __launch_bounds__(256) void t_reduce_kernel(
    const float* __restrict__ t_part, float* __restrict__ t) {
  int i = blockIdx.x * 256 + threadIdx.x;  // < 196608
  float s = 0.f;
#pragma unroll
  for (int nc = 0; nc < 16; ++nc) s += t_part[(size_t)nc * 196608 + i];
  t[i] = s;
}

// ---------------- LayerNorm + final projection ----------------
__global__ __launch_bounds__(256) void ln_out_kernel(
    const float* __restrict__ pooled, const float* __restrict__ Wo,
    const float* __restrict__ bo, const float* __restrict__ gamma,
    const float* __restrict__ beta, float* __restrict__ out) {
  __shared__ float wbuf[4];
  const int row = blockIdx.x, tid = threadIdx.x;
  float p[3];
#pragma unroll
  for (int u = 0; u < 3; u++) p[u] = pooled[(size_t)row * 768 + tid + u * 256];
  float s1 = p[0] + p[1] + p[2];
  float s2 = p[0] * p[0] + p[1] * p[1] + p[2] * p[2];
  s1 = block_reduce(s1, false, wbuf, tid);
  s2 = block_reduce(s2, false, wbuf, tid);
  float mean = s1 * (1.f / 768.f);
  float var = s2 * (1.f / 768.f) - mean * mean;
  float rstd = rsqrtf(var + LN_EPS);
  float accv = 0.f;
#pragma unroll
  for (int u = 0; u < 3; u++) {
    int i = tid + u * 256;
    float y = (p[u] - mean) * rstd * gamma[i] + beta[i];
    accv += y * Wo[i];
  }
  accv = block_reduce(accv, false, wbuf, tid);
  if (tid == 0) out[row] = accv + bo[0];
}

extern "C" void kernel_launch(void* const* d_in, const int* in_sizes, int n_in,
                              void* d_out, int out_size, void* d_ws, size_t ws_size,
                              hipStream_t stream) {
  const float* x = (const float*)d_in[0];
  const float* enc = (const float*)d_in[1];
  const int* dmask = (const int*)d_in[2];
  const int* amask = (const int*)d_in[3];
  const float* Wk = (const float*)d_in[4];
  const float* Wv = (const float*)d_in[5];
  const float* Wo = (const float*)d_in[6];
  const float* bo = (const float*)d_in[7];
  const float* gamma = (const float*)d_in[8];
  const float* beta = (const float*)d_in[9];
  float* out = (float*)d_out;

  char* ws = (char*)d_ws;
  size_t off = 0;
  auto alloc = [&](size_t bytes) -> char* {
    char* p = ws + off;
    off += (bytes + 255) & ~((size_t)255);
    return p;
  };
  _Float16* xh = (_Float16*)alloc((size_t)16384 * 768 * 2);
  _Float16* ench = (_Float16*)alloc((size_t)2048 * 768 * 2);
  _Float16* wkT = (_Float16*)alloc((size_t)768 * 768 * 2);
  _Float16* wvh = (_Float16*)alloc((size_t)768 * 768 * 2);
  _Float16* encKh = (_Float16*)alloc((size_t)2048 * 768 * 2);
  float* ca = (float*)alloc((size_t)4 * 64 * 4096 * 4);
  float* t_part = (float*)alloc((size_t)16 * 256 * 768 * 4);
  float* t = (float*)alloc((size_t)256 * 768 * 4);
  _Float16* th = (_Float16*)alloc((size_t)256 * 768 * 2);
  float* pooled = (float*)alloc((size_t)256 * 768 * 4);
  float4* stats = (float4*)alloc((size_t)4 * 2048 * 16);

  // batched path needs 4 S buffers (67.1 MB); fallback needs 1 (16.8 MB)
  const size_t s_one = (size_t)2048 * 4096 * 2;
  const bool batched = (off + 4 * s_one) <= ws_size;
  _Float16* S = (_Float16*)alloc(batched ? 4 * s_one : s_one);

  const float scale = 0.036084391824351615f;  // 1/sqrt(768)

  cast_f32_f16_kernel<<<12288, 256, 0, stream>>>(x, xh, 16384 * 768 / 4);
  cast_f32_f16_kernel<<<1536, 256, 0, stream>>>(enc, ench, 2048 * 768 / 4);
  cast_f32_f16_kernel<<<576, 256, 0, stream>>>(Wv, wvh, 768 * 768 / 4);
  transpose_f32_to_f16_kernel<<<dim3(24, 24), 256, 0, stream>>>(Wk, wkT, 768, 768);

  // encK = enc @ Wk   [2048 x 768]
  gemm_f16_kernel<false><<<dim3(16, 6), 256, 0, stream>>>(
      ench, wkT, encKh, 2048, 768, 768, 1.0f, 0, 0);

  if (batched) {
    gemm_f16_kernel<false><<<dim3(16, 32, 4), 256, 0, stream>>>(
        encKh, xh, S, 2048, 4096, 768, scale,
        (size_t)4096 * 768, (size_t)2048 * 4096);
    row_stats_kernel<<<dim3(2048, 1, 4), 256, 0, stream>>>(S, dmask, amask, stats);
    combine_kernel<<<dim3(64, 16, 4), 256, 0, stream>>>(S, stats, amask, ca);
  } else {
    for (int b = 0; b < 4; b++) {
      gemm_f16_kernel<false><<<dim3(16, 32), 256, 0, stream>>>(
          encKh, xh + (size_t)b * 4096 * 768, S, 2048, 4096, 768, scale, 0, 0);
      row_stats_kernel<<<dim3(2048, 1, 1), 256, 0, stream>>>(
          S, dmask, amask + (size_t)b * 4096, stats + (size_t)b * 2048);
      combine_kernel<<<dim3(64, 16, 1), 256, 0, stream>>>(
          S, stats + (size_t)b * 2048, amask + (size_t)b * 4096,
          ca + (size_t)b * 64 * 4096);
    }
  }

  // t = ca @ x  (fp32), split over n-chunks then reduced
  t_partial_kernel<<<dim3(12, 16, 4), 256, 0, stream>>>(ca, x, t_part);
  t_reduce_kernel<<<768, 256, 0, stream>>>(t_part, t);
  cast_f32_f16_kernel<<<192, 256, 0, stream>>>(t, th, 196608 / 4);
  // pooled = t @ Wv^T  [256 x 768] fp32
  gemm_f16_kernel<true><<<dim3(2, 6), 256, 0, stream>>>(
      th, wvh, pooled, 256, 768, 768, 1.0f, 0, 0);
  ln_out_kernel<<<256, 256, 0, stream>>>(pooled, Wo, bo, gamma, beta, out);
}

// Round 3
// 210.835 us; speedup vs baseline: 3.1010x; 1.0693x over previous
//
#include <hip/hip_runtime.h>
#include <hip/hip_bf16.h>
#include <hip/hip_fp16.h>

typedef _Float16 half8 __attribute__((ext_vector_type(8)));
typedef _Float16 half4 __attribute__((ext_vector_type(4)));
typedef _Float16 half2v __attribute__((ext_vector_type(2)));
typedef float f32x4 __attribute__((ext_vector_type(4)));

#define LN_EPS 1e-5f
#define MASK_FILL -1e9f

// async global->LDS, 16B per lane. LDS dest is wave-uniform base + lane*16.
__device__ __forceinline__ void async16(void* lds, const void* g) {
  __builtin_amdgcn_global_load_lds(
      (__attribute__((address_space(1))) void*)(g),
      (__attribute__((address_space(3))) void*)(lds), 16, 0, 0);
}

// ---------------- cast f32 -> f16 (vec4) ----------------
__global__ __launch_bounds__(256) void cast_f32_f16_kernel(
    const float* __restrict__ in, _Float16* __restrict__ out, int n4) {
  int i = blockIdx.x * 256 + threadIdx.x;
  if (i < n4) {
    float4 v = ((const float4*)in)[i];
    half4 h = { (_Float16)v.x, (_Float16)v.y, (_Float16)v.z, (_Float16)v.w };
    ((half4*)out)[i] = h;
  }
}

// ---------------- transpose f32 [R][C] -> f16 [C][R] ----------------
__global__ __launch_bounds__(256) void transpose_f32_to_f16_kernel(
    const float* __restrict__ in, _Float16* __restrict__ out, int R, int C) {
  __shared__ float tile[32][33];
  int bc = blockIdx.x * 32, br = blockIdx.y * 32;
  int lc = threadIdx.x & 31;
  int lr0 = threadIdx.x >> 5;  // 0..7
  for (int i = lr0; i < 32; i += 8)
    tile[i][lc] = in[(size_t)(br + i) * C + bc + lc];
  __syncthreads();
  for (int i = lr0; i < 32; i += 8)
    out[(size_t)(bc + i) * R + br + lc] = (_Float16)tile[lc][i];
}

// ---------------- fp16 MFMA GEMM, m97 structure ----------------
// C[M][N] = alpha * A[M][K] @ Bt[N][K]^T. 128x128 tile, BK=32, 4 waves (2x2),
// each wave 64x64 via 4x4 16x16x32 frags. global_load_lds(16B) staging into
// LINEAR [128][32] LDS tiles (gload_lds needs contiguous lane-order dest).
template<bool OUT_F32>
__global__ __launch_bounds__(256) void gemm_f16_kernel(
    const _Float16* __restrict__ A, const _Float16* __restrict__ Bt,
    void* __restrict__ C, int M, int N, int K, float alpha,
    size_t strideBt, size_t strideC) {
  __shared__ _Float16 As[128 * 32];
  __shared__ _Float16 Bs[128 * 32];
  const int tid = threadIdx.x;
  const int bm = blockIdx.x * 128, bn = blockIdx.y * 128;
  const size_t z = blockIdx.z;
  const int wave = tid >> 6, lane = tid & 63;
  const int wr = (wave >> 1) * 64, wc = (wave & 1) * 64;
  const int fr = lane & 15, kg = (lane >> 4) * 8;
  f32x4 acc[4][4] = {};
  // staging: wave w covers rows [w*32, w*32+32) in two 16-row issues.
  // issue: 64 lanes x 16B = 1024B = 16 rows of 64B; lane l -> row l/4, col (l&3)*8
  const int srow = wave * 32 + (lane >> 2);
  const int scol = (lane & 3) * 8;
  const _Float16* ga = A + (size_t)(bm + srow) * K + scol;
  const _Float16* gb = Bt + z * strideBt + (size_t)(bn + srow) * K + scol;
  _Float16* lA0 = &As[(wave * 32) * 32];
  _Float16* lA1 = &As[(wave * 32 + 16) * 32];
  _Float16* lB0 = &Bs[(wave * 32) * 32];
  _Float16* lB1 = &Bs[(wave * 32 + 16) * 32];
  for (int k0 = 0; k0 < K; k0 += 32) {
    __syncthreads();  // all waves done reading LDS from previous iter
    async16(lA0, ga + k0);
    async16(lA1, ga + (size_t)16 * K + k0);
    async16(lB0, gb + k0);
    async16(lB1, gb + (size_t)16 * K + k0);
    __syncthreads();  // drains vmcnt(0): staging complete
    half8 af[4], bf[4];
#pragma unroll
    for (int i = 0; i < 4; i++) af[i] = *(const half8*)&As[(wr + i * 16 + fr) * 32 + kg];
#pragma unroll
    for (int j = 0; j < 4; j++) bf[j] = *(const half8*)&Bs[(wc + j * 16 + fr) * 32 + kg];
#pragma unroll
    for (int i = 0; i < 4; i++)
#pragma unroll
      for (int j = 0; j < 4; j++)
        acc[i][j] = __builtin_amdgcn_mfma_f32_16x16x32_f16(af[i], bf[j], acc[i][j], 0, 0, 0);
  }
  const int rg = (lane >> 4) * 4;
#pragma unroll
  for (int i = 0; i < 4; i++) {
#pragma unroll
    for (int j = 0; j < 4; j++) {
      int col = bn + wc + j * 16 + fr;
#pragma unroll
      for (int r = 0; r < 4; r++) {
        int row = bm + wr + i * 16 + rg + r;
        float v = acc[i][j][r] * alpha;
        if (OUT_F32)
          ((float*)C)[z * strideC + (size_t)row * N + col] = v;
        else
          ((_Float16*)C)[z * strideC + (size_t)row * N + col] = (_Float16)v;
      }
    }
  }
}

// ---------------- block reduce helper (256 threads, 4 waves) ----------------
__device__ __forceinline__ float block_reduce(float v, bool do_max, float* wbuf, int tid) {
#pragma unroll
  for (int m = 32; m; m >>= 1) {
    float o = __shfl_xor(v, m);
    v = do_max ? fmaxf(v, o) : (v + o);
  }
  if ((tid & 63) == 0) wbuf[tid >> 6] = v;
  __syncthreads();
  float r = do_max ? fmaxf(fmaxf(wbuf[0], wbuf[1]), fmaxf(wbuf[2], wbuf[3]))
                   : (wbuf[0] + wbuf[1] + wbuf[2] + wbuf[3]);
  __syncthreads();
  return r;
}

// ---------------- pass 1: per-row masked softmax stats ----------------
// One block per S-row. stats[b*2048+row] = (rowmax, w/denom, dm_flag, 0)
__global__ __launch_bounds__(256) void row_stats_kernel(
    const _Float16* __restrict__ S, const int* __restrict__ dmask,
    const int* __restrict__ amask, float4* __restrict__ stats) {
  __shared__ float wbuf[4];
  const int row = blockIdx.x;  // 0..2047 (= kd*32+ds)
  const int b = blockIdx.z;
  const int tid = threadIdx.x;
  const int kd = row >> 5;
  const bool dm = dmask[row] != 0;
  int nv = 0;
#pragma unroll
  for (int i = 0; i < 32; i++) nv += (dmask[kd * 32 + i] != 0);
  const float w = nv ? (dm ? 1.0f / (float)nv : 0.0f) : (1.0f / 32.0f);
  if (w == 0.0f) {
    if (tid == 0) stats[(size_t)b * 2048 + row] = make_float4(0.f, 0.f, 0.f, 0.f);
    return;
  }
  const _Float16* sp = S + ((size_t)b * 2048 + row) * 4096;
  const int* am = amask + (size_t)b * 4096;
  float a[16];
#pragma unroll
  for (int h = 0; h < 2; h++) {
    half8 v = *(const half8*)(sp + h * 2048 + tid * 8);
    int4 m0 = *(const int4*)(am + h * 2048 + tid * 8);
    int4 m1 = *(const int4*)(am + h * 2048 + tid * 8 + 4);
    int mm[8] = {m0.x, m0.y, m0.z, m0.w, m1.x, m1.y, m1.z, m1.w};
#pragma unroll
    for (int u = 0; u < 8; u++)
      a[h * 8 + u] = (dm && mm[u] != 0) ? (float)v[u] : MASK_FILL;
  }
  float mx = a[0];
#pragma unroll
  for (int c = 1; c < 16; c++) mx = fmaxf(mx, a[c]);
  mx = block_reduce(mx, true, wbuf, tid);
  float ls = 0.f;
#pragma unroll
  for (int c = 0; c < 16; c++) ls += expf(a[c] - mx);
  float denom = block_reduce(ls, false, wbuf, tid);
  if (tid == 0)
    stats[(size_t)b * 2048 + row] = make_float4(mx, w / denom, dm ? 1.f : 0.f, 0.f);
}

// ---------------- pass 2: ds-weighted combine ----------------
// ca[b][kd][n] = sum_ds iw * exp(a - mx); each thread owns 2 n-columns.
__global__ __launch_bounds__(256) void combine_kernel(
    const _Float16* __restrict__ S, const float4* __restrict__ stats,
    const int* __restrict__ amask, float* __restrict__ ca) {
  const int kd = blockIdx.x;
  const int b = blockIdx.z;
  const int n0 = blockIdx.y * 512 + threadIdx.x * 2;
  const int* am = amask + (size_t)b * 4096;
  const bool nm0 = am[n0] != 0, nm1 = am[n0 + 1] != 0;
  const _Float16* sp = S + ((size_t)b * 2048 + kd * 32) * 4096 + n0;
  const float4* st = stats + (size_t)b * 2048 + kd * 32;
  float acc0 = 0.f, acc1 = 0.f;
#pragma unroll
  for (int ds = 0; ds < 32; ds++) {
    float4 s4 = st[ds];
    if (s4.y == 0.f) continue;
    half2v v = *(const half2v*)(sp + (size_t)ds * 4096);
    float a0 = (s4.z != 0.f && nm0) ? (float)v[0] : MASK_FILL;
    float a1 = (s4.z != 0.f && nm1) ? (float)v[1] : MASK_FILL;
    acc0 += s4.y * expf(a0 - s4.x);
    acc1 += s4.y * expf(a1 - s4.x);
  }
  float2 r = {acc0, acc1};
  *(float2*)&ca[((size_t)b * 64 + kd) * 4096 + n0] = r;
}

// ---------------- t partial: t[b*64+m][j] = sum_n ca[b][m][n] * x[b][n][j] ----
__global__ __launch_bounds__(256) void t_partial_kernel(
    const float* __restrict__ ca,   // [4][64][4096]
    const float* __restrict__ x,    // [4][4096][768]
    float* __restrict__ t_part) {   // [16][256][768]
  __shared__ float cas[64][68];
  __shared__ float xs[64][68];
  const int jt = blockIdx.x;  // 0..11
  const int nc = blockIdx.y;  // 0..15
  const int b = blockIdx.z;   // 0..3
  const int tid = threadIdx.x;
  const int tm = tid >> 4, tj = tid & 15;
  const int r = tid >> 2, cg = (tid & 3) * 16;
  float acc[4][4] = {};
  for (int n0 = nc * 256; n0 < nc * 256 + 256; n0 += 64) {
    __syncthreads();
    const float* cap = ca + ((size_t)(b * 64 + r)) * 4096 + n0 + cg;
    const float* xp = x + ((size_t)b * 4096 + n0 + r) * 768 + jt * 64 + cg;
#pragma unroll
    for (int u = 0; u < 16; u += 4) {
      *(float4*)&cas[r][cg + u] = *(const float4*)(cap + u);
      *(float4*)&xs[r][cg + u] = *(const float4*)(xp + u);
    }
    __syncthreads();
#pragma unroll 16
    for (int nn = 0; nn < 64; ++nn) {
      float cm[4], xj[4];
#pragma unroll
      for (int i = 0; i < 4; i++) cm[i] = cas[tm * 4 + i][nn];
#pragma unroll
      for (int j = 0; j < 4; j++) xj[j] = xs[nn][tj * 4 + j];
#pragma unroll
      for (int i = 0; i < 4; i++)
#pragma unroll
        for (int j = 0; j < 4; j++) acc[i][j] += cm[i] * xj[j];
    }
  }
#pragma unroll
  for (int i = 0; i < 4; i++)
#pragma unroll
    for (int j = 0; j < 4; j++)
      t_part[((size_t)nc * 256 + b * 64 + tm * 4 + i) * 768 + jt * 64 + tj * 4 + j] = acc[i][j];
}

__global__ __launch_bounds__(256) void t_reduce_kernel(
    const float* __restrict__ t_part, float* __restrict__ t) {
  int i = blockIdx.x * 256 + threadIdx.x;  // < 196608
  float s = 0.f;
#pragma unroll
  for (int nc = 0; nc < 16; ++nc) s += t_part[(size_t)nc * 196608 + i];
  t[i] = s;
}

// ---------------- LayerNorm + final projection ----------------
__global__ __launch_bounds__(256) void ln_out_kernel(
    const float* __restrict__ pooled, const float* __restrict__ Wo,
    const float* __restrict__ bo, const float* __restrict__ gamma,
    const float* __restrict__ beta, float* __restrict__ out) {
  __shared__ float wbuf[4];
  const int row = blockIdx.x, tid = threadIdx.x;
  float p[3];
#pragma unroll
  for (int u = 0; u < 3; u++) p[u] = pooled[(size_t)row * 768 + tid + u * 256];
  float s1 = p[0] + p[1] + p[2];
  float s2 = p[0] * p[0] + p[1] * p[1] + p[2] * p[2];
  s1 = block_reduce(s1, false, wbuf, tid);
  s2 = block_reduce(s2, false, wbuf, tid);
  float mean = s1 * (1.f / 768.f);
  float var = s2 * (1.f / 768.f) - mean * mean;
  float rstd = rsqrtf(var + LN_EPS);
  float accv = 0.f;
#pragma unroll
  for (int u = 0; u < 3; u++) {
    int i = tid + u * 256;
    float y = (p[u] - mean) * rstd * gamma[i] + beta[i];
    accv += y * Wo[i];
  }
  accv = block_reduce(accv, false, wbuf, tid);
  if (tid == 0) out[row] = accv + bo[0];
}

extern "C" void kernel_launch(void* const* d_in, const int* in_sizes, int n_in,
                              void* d_out, int out_size, void* d_ws, size_t ws_size,
                              hipStream_t stream) {
  const float* x = (const float*)d_in[0];
  const float* enc = (const float*)d_in[1];
  const int* dmask = (const int*)d_in[2];
  const int* amask = (const int*)d_in[3];
  const float* Wk = (const float*)d_in[4];
  const float* Wv = (const float*)d_in[5];
  const float* Wo = (const float*)d_in[6];
  const float* bo = (const float*)d_in[7];
  const float* gamma = (const float*)d_in[8];
  const float* beta = (const float*)d_in[9];
  float* out = (float*)d_out;

  char* ws = (char*)d_ws;
  size_t off = 0;
  auto alloc = [&](size_t bytes) -> char* {
    char* p = ws + off;
    off += (bytes + 255) & ~((size_t)255);
    return p;
  };
  _Float16* xh = (_Float16*)alloc((size_t)16384 * 768 * 2);
  _Float16* ench = (_Float16*)alloc((size_t)2048 * 768 * 2);
  _Float16* wkT = (_Float16*)alloc((size_t)768 * 768 * 2);
  _Float16* wvh = (_Float16*)alloc((size_t)768 * 768 * 2);
  _Float16* encKh = (_Float16*)alloc((size_t)2048 * 768 * 2);
  float* ca = (float*)alloc((size_t)4 * 64 * 4096 * 4);
  float* t_part = (float*)alloc((size_t)16 * 256 * 768 * 4);
  float* t = (float*)alloc((size_t)256 * 768 * 4);
  _Float16* th = (_Float16*)alloc((size_t)256 * 768 * 2);
  float* pooled = (float*)alloc((size_t)256 * 768 * 4);
  float4* stats = (float4*)alloc((size_t)4 * 2048 * 16);

  // batched path needs 4 S buffers (67.1 MB); fallback needs 1 (16.8 MB)
  const size_t s_one = (size_t)2048 * 4096 * 2;
  const bool batched = (off + 4 * s_one) <= ws_size;
  _Float16* S = (_Float16*)alloc(batched ? 4 * s_one : s_one);

  const float scale = 0.036084391824351615f;  // 1/sqrt(768)

  cast_f32_f16_kernel<<<12288, 256, 0, stream>>>(x, xh, 16384 * 768 / 4);
  cast_f32_f16_kernel<<<1536, 256, 0, stream>>>(enc, ench, 2048 * 768 / 4);
  cast_f32_f16_kernel<<<576, 256, 0, stream>>>(Wv, wvh, 768 * 768 / 4);
  transpose_f32_to_f16_kernel<<<dim3(24, 24), 256, 0, stream>>>(Wk, wkT, 768, 768);

  // encK = enc @ Wk   [2048 x 768]
  gemm_f16_kernel<false><<<dim3(16, 6), 256, 0, stream>>>(
      ench, wkT, encKh, 2048, 768, 768, 1.0f, 0, 0);

  if (batched) {
    gemm_f16_kernel<false><<<dim3(16, 32, 4), 256, 0, stream>>>(
        encKh, xh, S, 2048, 4096, 768, scale,
        (size_t)4096 * 768, (size_t)2048 * 4096);
    row_stats_kernel<<<dim3(2048, 1, 4), 256, 0, stream>>>(S, dmask, amask, stats);
    combine_kernel<<<dim3(64, 8, 4), 256, 0, stream>>>(S, stats, amask, ca);
  } else {
    for (int b = 0; b < 4; b++) {
      gemm_f16_kernel<false><<<dim3(16, 32), 256, 0, stream>>>(
          encKh, xh + (size_t)b * 4096 * 768, S, 2048, 4096, 768, scale, 0, 0);
      row_stats_kernel<<<dim3(2048, 1, 1), 256, 0, stream>>>(
          S, dmask, amask + (size_t)b * 4096, stats + (size_t)b * 2048);
      combine_kernel<<<dim3(64, 8, 1), 256, 0, stream>>>(
          S, stats + (size_t)b * 2048, amask + (size_t)b * 4096,
          ca + (size_t)b * 64 * 4096);
    }
  }

  // t = ca @ x  (fp32), split over n-chunks then reduced
  t_partial_kernel<<<dim3(12, 16, 4), 256, 0, stream>>>(ca, x, t_part);
  t_reduce_kernel<<<768, 256, 0, stream>>>(t_part, t);
  cast_f32_f16_kernel<<<192, 256, 0, stream>>>(t, th, 196608 / 4);
  // pooled = t @ Wv^T  [256 x 768] fp32
  gemm_f16_kernel<true><<<dim3(2, 6), 256, 0, stream>>>(
      th, wvh, pooled, 256, 768, 768, 1.0f, 0, 0);
  ln_out_kernel<<<256, 256, 0, stream>>>(pooled, Wo, bo, gamma, beta, out);
}